// Round 4
// baseline (328.099 us; speedup 1.0000x reference)
//
#include <hip/hip_runtime.h>

#define C_IN   128
#define H_IN   56
#define W_IN   56
#define HW     3136      // 56*56
#define CHW    401408    // 128*3136
#define O_OUT  256
#define OHW    802816    // 256*3136
#define HP     58
#define WP     58
#define HWP    3364      // 58*58 padded image plane
#define BN     128
#define LDK    72        // fallback padded layout

typedef __bf16 bf16x8 __attribute__((ext_vector_type(8)));
typedef float  f32x4  __attribute__((ext_vector_type(4)));
typedef unsigned short ushort_t;
typedef ushort_t ushort8 __attribute__((ext_vector_type(8)));
typedef unsigned int u32;

__device__ __forceinline__ ushort_t f2bf(float f) {
    union { float f; unsigned u; } v; v.f = f;
    unsigned r = (v.u + 0x7fffu + ((v.u >> 16) & 1u)) >> 16;
    return (ushort_t)r;
}

// direct-to-LDS 16B DMA: LDS dest must be wave-uniform base + lane*16
__device__ __forceinline__ void gload_lds16(const ushort_t* g, ushort_t* l) {
    __builtin_amdgcn_global_load_lds(
        (const __attribute__((address_space(1))) u32*)g,
        (__attribute__((address_space(3))) u32*)l, 16, 0, 0);
}

// Weights: w[o][c][kh][kw] fp32 -> wbf[pos][o][c] bf16, pos = kh*3+kw
__global__ void wt_kernel(const float* __restrict__ w, ushort_t* __restrict__ wbf) {
    int idx = blockIdx.x * 256 + threadIdx.x;        // 294912
    if (idx >= 9 * 256 * 128) return;
    int pos = idx >> 15;
    int rem = idx & 32767;
    int o   = rem >> 7;
    int c   = rem & 127;
    wbf[idx] = f2bf(w[o * 1152 + c * 9 + pos]);
}

// Zero the padded border of xbp (ws is poisoned 0xAA every call)
__global__ void bz_kernel(ushort_t* __restrict__ xbp) {
    int idx = blockIdx.x * 256 + threadIdx.x;        // 32*228*16 = 116736
    if (idx >= 32 * 228 * 16) return;
    int grp = idx & 15;
    int bp  = (idx >> 4) % 228;
    int n   = (idx >> 4) / 228;
    int h_p, w_p;
    if (bp < 58)       { h_p = 0;  w_p = bp; }
    else if (bp < 116) { h_p = 57; w_p = bp - 58; }
    else { int r = bp - 116; h_p = 1 + (r >> 1); w_p = (r & 1) ? 57 : 0; }
    ushort8 z = ushort8{0,0,0,0,0,0,0,0};
    *(ushort8*)(xbp + ((long)n * HWP + h_p * WP + w_p) * 128 + grp * 8) = z;
}

// x fp32 NCHW -> bf16 padded NHWC. Tile = 64 pixels x 128 ch, pair-packed LDS transpose.
__global__ __launch_bounds__(256)
void xt_kernel(const float* __restrict__ x, ushort_t* __restrict__ xbp) {
    __shared__ u32 T[64 * 65];           // [pix 0..63][cpair 0..63], stride 65 dw (2-way banks)
    const int t  = threadIdx.x;
    const int tb = blockIdx.x;           // 0..1567
    const int n   = tb / 49;
    const int hw0 = (tb - n * 49) * 64;
    const float* src = x + (long)n * CHW + hw0;

    #pragma unroll
    for (int i = 0; i < 4; ++i) {
        const int cpair = i * 16 + (t >> 4);   // 0..63
        const int p4    = t & 15;
        f32x4 a = *(const f32x4*)(src + (long)(2 * cpair) * HW + p4 * 4);
        f32x4 b = *(const f32x4*)(src + (long)(2 * cpair + 1) * HW + p4 * 4);
        #pragma unroll
        for (int j = 0; j < 4; ++j) {
            u32 pack = (u32)f2bf(a[j]) | ((u32)f2bf(b[j]) << 16);
            T[(p4 * 4 + j) * 65 + cpair] = pack;
        }
    }
    __syncthreads();

    #pragma unroll
    for (int s = 0; s < 4; ++s) {
        const int idx = s * 256 + t;     // 1024 = 64 pix * 16 grp
        const int pix = idx >> 4;
        const int g   = idx & 15;
        u32 d0 = T[pix * 65 + g * 4 + 0];
        u32 d1 = T[pix * 65 + g * 4 + 1];
        u32 d2 = T[pix * 65 + g * 4 + 2];
        u32 d3 = T[pix * 65 + g * 4 + 3];
        const int hw = hw0 + pix;
        const int h  = hw / 56;
        const int w  = hw - h * 56;
        u32* dst = (u32*)(xbp + ((long)n * HWP + (h + 1) * WP + (w + 1)) * 128 + g * 8);
        dst[0] = d0; dst[1] = d1; dst[2] = d2; dst[3] = d3;
    }
}

// Fast conv: A (weights) global->regs from L2, B (pixels) DMA->LDS double-buffered,
// one barrier per kernel position. Block tile 256 o x 128 pix, wave tile 64x64.
__global__ __launch_bounds__(512, 4)
void conv3_kernel(const ushort_t* __restrict__ xbp, const ushort_t* __restrict__ wbf,
                  const float* __restrict__ bias, float* __restrict__ out) {
    __shared__ ushort_t Bs[2][BN * 128];    // 2 x 32768 B

    const int tid  = threadIdx.x;
    const int lane = tid & 63;
    const int wave = tid >> 6;
    const int wm   = wave >> 1;
    const int wn   = wave & 1;
    const int l15  = lane & 15;
    const int quad = lane >> 4;
    const int pix_base = blockIdx.x * BN;

    // staging map: LDS 16B-slot s = r*512 + tid  ->  (pix = s>>4, g_sw = s&15),
    // holding source channel-group g = g_sw ^ (pix&15)  (swizzle done at load time)
    const int spx = tid >> 4;            // 0..31
    const int gsw = tid & 15;
    int sbase[4];                        // ushort index into xbp, pos-independent
    #pragma unroll
    for (int r = 0; r < 4; ++r) {
        const int pix = r * 32 + spx;
        const int p   = pix_base + pix;
        const int n   = p / HW;
        const int hw  = p - n * HW;
        const int h   = hw / W_IN;
        const int w   = hw - h * W_IN;
        const int g   = gsw ^ (pix & 15);
        sbase[r] = (int)(((long)n * HWP + (h + 1) * WP + (w + 1)) * 128 + g * 8);
    }

    f32x4 acc[4][4];
    #pragma unroll
    for (int t = 0; t < 4; ++t)
        #pragma unroll
        for (int u = 0; u < 4; ++u)
            acc[t][u] = f32x4{0.f, 0.f, 0.f, 0.f};

    // pos -> padded-layout ushort offset (dh*WP + dw)*128, compile-time
    // stage pos 0
    {
        #pragma unroll
        for (int r = 0; r < 4; ++r)
            gload_lds16(xbp + sbase[r] + (-WP - 1) * 128, &Bs[0][(r * 512 + tid) * 8]);
    }
    __syncthreads();

    #pragma unroll
    for (int pos = 0; pos < 9; ++pos) {
        const int cur = pos & 1;
        if (pos < 8) {
            const int npos = pos + 1;
            const int dh = npos / 3 - 1;
            const int dw = npos - (npos / 3) * 3 - 1;
            const int off = (dh * WP + dw) * 128;
            #pragma unroll
            for (int r = 0; r < 4; ++r)
                gload_lds16(xbp + sbase[r] + off, &Bs[1 - cur][(r * 512 + tid) * 8]);
        }
        const ushort_t* wsrc = wbf + pos * 32768;

        #pragma unroll
        for (int ks = 0; ks < 4; ++ks) {
            bf16x8 af[4], bfv[4];
            #pragma unroll
            for (int t = 0; t < 4; ++t) {
                const int o = wm * 64 + t * 16 + l15;
                af[t] = *(const bf16x8*)(wsrc + o * 128 + ks * 32 + quad * 8);
            }
            const int gk = ks * 4 + quad;
            #pragma unroll
            for (int u = 0; u < 4; ++u) {
                const int col = wn * 64 + u * 16 + l15;
                bfv[u] = *(const bf16x8*)(&Bs[cur][col * 128 + ((gk ^ (col & 15)) * 8)]);
            }
            #pragma unroll
            for (int t = 0; t < 4; ++t)
                #pragma unroll
                for (int u = 0; u < 4; ++u)
                    acc[t][u] = __builtin_amdgcn_mfma_f32_16x16x32_bf16(af[t], bfv[u], acc[t][u], 0, 0, 0);
        }
        __syncthreads();   // all reads of Bs[cur] done; DMA of Bs[1-cur] drained (vmcnt(0) at barrier)
    }

    #pragma unroll
    for (int u = 0; u < 4; ++u) {
        const int col = wn * 64 + u * 16 + l15;
        const int pp  = pix_base + col;
        const int nn  = pp / HW;
        const int hw2 = pp - nn * HW;
        const long obase = (long)nn * OHW + hw2;
        #pragma unroll
        for (int t = 0; t < 4; ++t) {
            const int o_base = wm * 64 + t * 16 + quad * 4;
            #pragma unroll
            for (int r = 0; r < 4; ++r) {
                const int o = o_base + r;
                out[obase + (long)o * HW] = acc[t][u][r] + bias[o];
            }
        }
    }
}

// ---- Fallback (round-1, known-correct): used only if ws can't hold padded xbp ----
__global__ __launch_bounds__(512, 4)
void conv_kernel(const float* __restrict__ x, const ushort_t* __restrict__ wbf,
                 const float* __restrict__ bias, float* __restrict__ out) {
    __shared__ ushort_t As[256 * LDK];
    __shared__ ushort_t Bs[BN * LDK];

    const int tid  = threadIdx.x;
    const int lane = tid & 63;
    const int wave = tid >> 6;
    const int wm   = wave >> 1;
    const int wn   = wave & 1;
    const int l15  = lane & 15;
    const int quad = lane >> 4;

    const int pix_base = blockIdx.x * BN;
    const int px  = tid & 127;
    const int cg0 = tid >> 7;
    const int p   = pix_base + px;
    const int n_img = p / HW;
    const int hw    = p - n_img * HW;
    const int h     = hw / W_IN;
    const int w_    = hw - h * W_IN;
    const float* ximg = x + (long)n_img * CHW;

    f32x4 acc[4][4];
    #pragma unroll
    for (int t = 0; t < 4; ++t)
        #pragma unroll
        for (int u = 0; u < 4; ++u)
            acc[t][u] = f32x4{0.f, 0.f, 0.f, 0.f};

    for (int pos = 0; pos < 9; ++pos) {
        const int dh = pos / 3 - 1;
        const int dw = pos - (pos / 3) * 3 - 1;
        const int ih = h + dh;
        const int iw = w_ + dw;
        const bool valid = ((unsigned)ih < (unsigned)H_IN) && ((unsigned)iw < (unsigned)W_IN);
        const float* xsrc = ximg + ih * W_IN + iw;

        for (int half = 0; half < 2; ++half) {
            const int c0 = half * 64;
            {
                const ushort_t* wsrc = wbf + ((pos * 256) << 7) + c0;
                #pragma unroll
                for (int s = 0; s < 4; ++s) {
                    const int o  = (tid >> 3) + s * 64;
                    const int cg = tid & 7;
                    ushort8 v = *(const ushort8*)(wsrc + (o << 7) + cg * 8);
                    *(ushort8*)(&As[o * LDK + cg * 8]) = v;
                }
            }
            {
                #pragma unroll
                for (int s = 0; s < 2; ++s) {
                    const int cg = cg0 + s * 4;
                    const float* src = xsrc + (long)(c0 + cg * 8) * HW;
                    ushort8 v;
                    #pragma unroll
                    for (int j = 0; j < 8; ++j) {
                        float f = valid ? src[j * HW] : 0.0f;
                        v[j] = f2bf(f);
                    }
                    *(ushort8*)(&Bs[px * LDK + cg * 8]) = v;
                }
            }
            __syncthreads();

            #pragma unroll
            for (int ks = 0; ks < 2; ++ks) {
                bf16x8 af[4], bfv[4];
                #pragma unroll
                for (int t = 0; t < 4; ++t) {
                    const int row = wm * 64 + t * 16 + l15;
                    af[t] = *(const bf16x8*)(&As[row * LDK + ks * 32 + quad * 8]);
                }
                #pragma unroll
                for (int u = 0; u < 4; ++u) {
                    const int col = wn * 64 + u * 16 + l15;
                    bfv[u] = *(const bf16x8*)(&Bs[col * LDK + ks * 32 + quad * 8]);
                }
                #pragma unroll
                for (int t = 0; t < 4; ++t)
                    #pragma unroll
                    for (int u = 0; u < 4; ++u)
                        acc[t][u] = __builtin_amdgcn_mfma_f32_16x16x32_bf16(af[t], bfv[u], acc[t][u], 0, 0, 0);
            }
            __syncthreads();
        }
    }

    #pragma unroll
    for (int u = 0; u < 4; ++u) {
        const int col = wn * 64 + u * 16 + l15;
        const int pp  = pix_base + col;
        const int nn  = pp / HW;
        const int hw2 = pp - nn * HW;
        const long obase = (long)nn * OHW + hw2;
        #pragma unroll
        for (int t = 0; t < 4; ++t) {
            const int o_base = wm * 64 + t * 16 + quad * 4;
            #pragma unroll
            for (int r = 0; r < 4; ++r) {
                const int o = o_base + r;
                out[obase + (long)o * HW] = acc[t][u][r] + bias[o];
            }
        }
    }
}

extern "C" void kernel_launch(void* const* d_in, const int* in_sizes, int n_in,
                              void* d_out, int out_size, void* d_ws, size_t ws_size,
                              hipStream_t stream) {
    const float* x    = (const float*)d_in[0];
    const float* w    = (const float*)d_in[1];
    const float* bias = (const float*)d_in[2];
    float* out        = (float*)d_out;

    ushort_t* wbf = (ushort_t*)d_ws;                       // 589,824 B
    ushort_t* xbp = (ushort_t*)((char*)d_ws + 589824);     // 32*3364*128*2 = 27,557,888 B

    const size_t need = 589824u + 27557888u;

    hipLaunchKernelGGL(wt_kernel, dim3(1152), dim3(256), 0, stream, w, wbf);
    if (ws_size >= need) {
        hipLaunchKernelGGL(bz_kernel, dim3(456), dim3(256), 0, stream, xbp);
        hipLaunchKernelGGL(xt_kernel, dim3(1568), dim3(256), 0, stream, x, xbp);
        hipLaunchKernelGGL(conv3_kernel, dim3(100352 / BN), dim3(512), 0, stream,
                           xbp, wbf, bias, out);
    } else {
        hipLaunchKernelGGL(conv_kernel, dim3(100352 / BN), dim3(512), 0, stream,
                           x, wbf, bias, out);
    }
}